// Round 1
// baseline (157.826 us; speedup 1.0000x reference)
//
#include <hip/hip_runtime.h>
#include <math.h>

// knnLoss: B=4, N=8192, k=3. Brute-force 3-NN with LDS target tiles.
#define BATCH 4
#define NPTS 8192
#define TILE 2048          // targets staged per block (32 KB LDS as float4)
#define TSPLIT 4           // NPTS / TILE target chunks (merged in kernel 2)
#define SRC_PER_BLOCK 512  // 256 threads x 2 sources
#define SRC_CHUNKS 16      // NPTS / SRC_PER_BLOCK

// Branchless insert into sorted ascending triple (3 smallest seen).
__device__ __forceinline__ void insert3(float d, float& a0, float& a1, float& a2) {
    float h0 = fmaxf(a0, d);  a0 = fminf(a0, d);
    float h1 = fmaxf(a1, h0); a1 = fminf(a1, h0);
    a2 = fminf(a2, h1);
}

__global__ __launch_bounds__(256) void knn_partial(const float* __restrict__ src,
                                                   const float* __restrict__ tgt,
                                                   float* __restrict__ part) {
    __shared__ float4 ts[TILE];
    const int tid = threadIdx.x;
    const int sc = blockIdx.x, tc = blockIdx.y, b = blockIdx.z;

    // Stage target chunk: (x, y, z, t2) with invalid (0,0,0) points sentineled.
    const float* tgtb = tgt + ((size_t)b * NPTS + (size_t)tc * TILE) * 3;
    for (int j = tid; j < TILE; j += 256) {
        float x = tgtb[3 * j + 0];
        float y = tgtb[3 * j + 1];
        float z = tgtb[3 * j + 2];
        float t2 = x * x + y * y + z * z;
        bool valid = (x != 0.f) || (y != 0.f) || (z != 0.f);
        ts[j] = make_float4(x, y, z, valid ? t2 : 3.0e38f);
    }
    __syncthreads();

    // Two sources per thread (independent chains -> ILP, halves LDS reads/pair).
    const int i0 = sc * SRC_PER_BLOCK + tid;
    const int i1 = i0 + 256;
    const float* sp0 = src + ((size_t)b * NPTS + i0) * 3;
    const float* sp1 = src + ((size_t)b * NPTS + i1) * 3;
    float ax = sp0[0], ay = sp0[1], az = sp0[2];
    float bx = sp1[0], by = sp1[1], bz = sp1[2];
    float as2 = ax * ax + ay * ay + az * az;
    float bs2 = bx * bx + by * by + bz * bz;
    float nax = -2.f * ax, nay = -2.f * ay, naz = -2.f * az;
    float nbx = -2.f * bx, nby = -2.f * by, nbz = -2.f * bz;

    float a0 = 3e38f, a1 = 3e38f, a2 = 3e38f;
    float c0 = 3e38f, c1 = 3e38f, c2 = 3e38f;

    #pragma unroll 4
    for (int j = 0; j < TILE; ++j) {
        float4 t = ts[j];  // same-address broadcast ds_read_b128 across the wave
        float da = fmaf(nax, t.x, fmaf(nay, t.y, fmaf(naz, t.z, as2 + t.w)));
        float db = fmaf(nbx, t.x, fmaf(nby, t.y, fmaf(nbz, t.z, bs2 + t.w)));
        da = fmaxf(da, 0.f);  // jnp.maximum(d2, 0)
        db = fmaxf(db, 0.f);
        insert3(da, a0, a1, a2);
        insert3(db, c0, c1, c2);
    }

    // Partial results: squared distances, [B*N][TSPLIT][3]
    size_t o0 = (((size_t)b * NPTS + i0) * TSPLIT + tc) * 3;
    part[o0 + 0] = a0; part[o0 + 1] = a1; part[o0 + 2] = a2;
    size_t o1 = (((size_t)b * NPTS + i1) * TSPLIT + tc) * 3;
    part[o1 + 0] = c0; part[o1 + 1] = c1; part[o1 + 2] = c2;
}

__global__ __launch_bounds__(256) void knn_merge(const float* __restrict__ src,
                                                 const float* __restrict__ part,
                                                 float* __restrict__ acc,
                                                 float* __restrict__ cnt) {
    const int gid = blockIdx.x * 256 + threadIdx.x;  // 0 .. B*NPTS-1
    const int b = gid >> 13;                         // NPTS = 8192; uniform per block

    const float* p = part + (size_t)gid * (TSPLIT * 3);
    float m0 = 3e38f, m1 = 3e38f, m2 = 3e38f;
    #pragma unroll
    for (int q = 0; q < TSPLIT * 3; ++q) insert3(p[q], m0, m1, m2);

    float sx = src[(size_t)gid * 3 + 0];
    float sy = src[(size_t)gid * 3 + 1];
    float sz = src[(size_t)gid * 3 + 2];
    bool valid = (sx != 0.f) || (sy != 0.f) || (sz != 0.f);
    float s = valid ? (sqrtf(m0) + sqrtf(m1) + sqrtf(m2)) : 0.f;
    float c = valid ? 1.f : 0.f;

    // wave(64) shuffle reduce, then cross-wave via LDS
    for (int off = 32; off >= 1; off >>= 1) {
        s += __shfl_down(s, off);
        c += __shfl_down(c, off);
    }
    __shared__ float red_s[4], red_c[4];
    int wave = threadIdx.x >> 6, lane = threadIdx.x & 63;
    if (lane == 0) { red_s[wave] = s; red_c[wave] = c; }
    __syncthreads();
    if (threadIdx.x == 0) {
        float bs = red_s[0] + red_s[1] + red_s[2] + red_s[3];
        float bc = red_c[0] + red_c[1] + red_c[2] + red_c[3];
        atomicAdd(&acc[b], bs);
        atomicAdd(&cnt[b], bc);
    }
}

__global__ void knn_final(const float* __restrict__ acc,
                          const float* __restrict__ cnt,
                          float* __restrict__ out) {
    float loss = 0.f;
    #pragma unroll
    for (int b = 0; b < BATCH; ++b) loss += acc[b] / (cnt[b] * 3.0f);
    out[0] = loss * (1.0f / BATCH);
}

extern "C" void kernel_launch(void* const* d_in, const int* in_sizes, int n_in,
                              void* d_out, int out_size, void* d_ws, size_t ws_size,
                              hipStream_t stream) {
    const float* src = (const float*)d_in[0];
    const float* tgt = (const float*)d_in[1];
    float* out = (float*)d_out;

    // ws layout: [0,32): acc[4] + cnt[4] floats; [256, 256+1.5MB): partials
    float* acc = (float*)d_ws;
    float* cnt = acc + 4;
    float* part = (float*)((char*)d_ws + 256);

    hipMemsetAsync(d_ws, 0, 256, stream);

    dim3 g1(SRC_CHUNKS, TSPLIT, BATCH);  // 256 blocks
    knn_partial<<<g1, 256, 0, stream>>>(src, tgt, part);

    knn_merge<<<dim3((BATCH * NPTS) / 256), 256, 0, stream>>>(src, part, acc, cnt);

    knn_final<<<1, 1, 0, stream>>>(acc, cnt, out);
}

// Round 2
// 123.468 us; speedup vs baseline: 1.2783x; 1.2783x over previous
//
#include <hip/hip_runtime.h>
#include <math.h>

// knnLoss: B=4, N=8192, k=3. Brute-force 3-NN, LDS target tiles, packed fp32.
#define BATCH 4
#define NPTS 8192
#define TILE 512            // targets per block tile (pair-interleaved, 8 KB LDS)
#define TSPLIT 16           // NPTS / TILE target chunks
#define SRC_PER_THREAD 4
#define SRC_PER_BLOCK 1024  // 256 threads x 4 sources
#define SRC_CHUNKS 8        // NPTS / SRC_PER_BLOCK
#define NSRC_TOT (BATCH * NPTS)  // 32768

typedef __attribute__((ext_vector_type(2))) float f2;

// Branchless insert into sorted ascending triple; 4 ops via med3.
// a0<=a1<=a2 are the 3 smallest seen.
__device__ __forceinline__ void insert3(float d, float& a0, float& a1, float& a2) {
    float h  = fmaxf(a1, d);
    float m  = __builtin_amdgcn_fmed3f(a0, a1, d);
    a2 = fminf(a2, h);
    a1 = m;
    a0 = fminf(a0, d);
}

__global__ __launch_bounds__(256) void knn_partial(const float* __restrict__ src,
                                                   const float* __restrict__ tgt,
                                                   float* __restrict__ part) {
    // Pair-interleaved tile: entry e holds targets 2e,2e+1 as
    // {x0,x1, y0,y1, z0,z1, w0,w1}  (w = |t|^2, sentinel for invalid)
    __shared__ f2 ts[TILE / 2 * 4];
    const int tid = threadIdx.x;
    const int sc = blockIdx.x, tc = blockIdx.y, b = blockIdx.z;

    // Stage: thread t owns entry t (targets 2t, 2t+1).
    {
        const float* tb = tgt + ((size_t)b * NPTS + (size_t)tc * TILE + 2 * tid) * 3;
        float x0 = tb[0], y0 = tb[1], z0 = tb[2];
        float x1 = tb[3], y1 = tb[4], z1 = tb[5];
        float w0 = x0 * x0 + y0 * y0 + z0 * z0;
        float w1 = x1 * x1 + y1 * y1 + z1 * z1;
        if (!(x0 != 0.f || y0 != 0.f || z0 != 0.f)) w0 = 3.0e38f;
        if (!(x1 != 0.f || y1 != 0.f || z1 != 0.f)) w1 = 3.0e38f;
        ts[tid * 4 + 0] = (f2){x0, x1};
        ts[tid * 4 + 1] = (f2){y0, y1};
        ts[tid * 4 + 2] = (f2){z0, z1};
        ts[tid * 4 + 3] = (f2){w0, w1};
    }
    __syncthreads();

    // 4 sources per thread; packed precomputes duplicated into both halves.
    f2 nx[SRC_PER_THREAD], ny[SRC_PER_THREAD], nz[SRC_PER_THREAD], s2[SRC_PER_THREAD];
    #pragma unroll
    for (int s = 0; s < SRC_PER_THREAD; ++s) {
        int i = sc * SRC_PER_BLOCK + tid + 256 * s;
        const float* sp = src + ((size_t)b * NPTS + i) * 3;
        float ax = sp[0], ay = sp[1], az = sp[2];
        float q = ax * ax + ay * ay + az * az;
        nx[s] = (f2){-2.f * ax, -2.f * ax};
        ny[s] = (f2){-2.f * ay, -2.f * ay};
        nz[s] = (f2){-2.f * az, -2.f * az};
        s2[s] = (f2){q, q};
    }

    // Two chains per source (even/odd targets), merged at the end.
    float e0[SRC_PER_THREAD], e1[SRC_PER_THREAD], e2[SRC_PER_THREAD];
    float o0[SRC_PER_THREAD], o1[SRC_PER_THREAD], o2[SRC_PER_THREAD];
    #pragma unroll
    for (int s = 0; s < SRC_PER_THREAD; ++s) {
        e0[s] = e1[s] = e2[s] = 3e38f;
        o0[s] = o1[s] = o2[s] = 3e38f;
    }

    #pragma unroll 4
    for (int e = 0; e < TILE / 2; ++e) {
        f2 xs = ts[e * 4 + 0];
        f2 ys = ts[e * 4 + 1];
        f2 zs = ts[e * 4 + 2];
        f2 ws = ts[e * 4 + 3];
        #pragma unroll
        for (int s = 0; s < SRC_PER_THREAD; ++s) {
            f2 d = xs * nx[s] + (ys * ny[s] + (zs * nz[s] + (ws + s2[s])));
            insert3(d.x, e0[s], e1[s], e2[s]);
            insert3(d.y, o0[s], o1[s], o2[s]);
        }
    }

    // Merge odd chain into even chain, write sorted triple.
    // Layout: part[(tc*3 + q) * NSRC_TOT + flat_src]  (coalesced store & load)
    #pragma unroll
    for (int s = 0; s < SRC_PER_THREAD; ++s) {
        insert3(o0[s], e0[s], e1[s], e2[s]);
        insert3(o1[s], e0[s], e1[s], e2[s]);
        insert3(o2[s], e0[s], e1[s], e2[s]);
        size_t flat = (size_t)b * NPTS + sc * SRC_PER_BLOCK + tid + 256 * s;
        part[((size_t)tc * 3 + 0) * NSRC_TOT + flat] = e0[s];
        part[((size_t)tc * 3 + 1) * NSRC_TOT + flat] = e1[s];
        part[((size_t)tc * 3 + 2) * NSRC_TOT + flat] = e2[s];
    }
}

__global__ __launch_bounds__(256) void knn_merge(const float* __restrict__ src,
                                                 const float* __restrict__ part,
                                                 float* __restrict__ acc,
                                                 float* __restrict__ cnt,
                                                 unsigned* __restrict__ ticket,
                                                 float* __restrict__ out) {
    const int gid = blockIdx.x * 256 + threadIdx.x;  // 0 .. NSRC_TOT-1
    const int b = gid >> 13;                         // uniform per block (8192/256=32)

    float m0 = part[0 * NSRC_TOT + gid];
    float m1 = part[1 * NSRC_TOT + gid];
    float m2 = part[2 * NSRC_TOT + gid];
    #pragma unroll
    for (int q = 3; q < TSPLIT * 3; ++q)
        insert3(part[(size_t)q * NSRC_TOT + gid], m0, m1, m2);

    float sx = src[(size_t)gid * 3 + 0];
    float sy = src[(size_t)gid * 3 + 1];
    float sz = src[(size_t)gid * 3 + 2];
    bool valid = (sx != 0.f) || (sy != 0.f) || (sz != 0.f);
    float s = valid ? (sqrtf(fmaxf(m0, 0.f)) + sqrtf(fmaxf(m1, 0.f)) + sqrtf(fmaxf(m2, 0.f)))
                    : 0.f;
    float c = valid ? 1.f : 0.f;

    for (int off = 32; off >= 1; off >>= 1) {
        s += __shfl_down(s, off);
        c += __shfl_down(c, off);
    }
    __shared__ float red_s[4], red_c[4];
    int wave = threadIdx.x >> 6, lane = threadIdx.x & 63;
    if (lane == 0) { red_s[wave] = s; red_c[wave] = c; }
    __syncthreads();
    if (threadIdx.x == 0) {
        float bs = red_s[0] + red_s[1] + red_s[2] + red_s[3];
        float bc = red_c[0] + red_c[1] + red_c[2] + red_c[3];
        atomicAdd(&acc[b], bs);
        atomicAdd(&cnt[b], bc);
        __threadfence();
        unsigned t = atomicAdd(ticket, 1u);
        if (t == (unsigned)(gridDim.x - 1)) {
            float loss = 0.f;
            #pragma unroll
            for (int bb = 0; bb < BATCH; ++bb) {
                float as = atomicAdd(&acc[bb], 0.f);  // device-coherent read
                float ac = atomicAdd(&cnt[bb], 0.f);
                loss += as / (ac * 3.0f);
            }
            out[0] = loss * (1.0f / BATCH);
        }
    }
}

extern "C" void kernel_launch(void* const* d_in, const int* in_sizes, int n_in,
                              void* d_out, int out_size, void* d_ws, size_t ws_size,
                              hipStream_t stream) {
    const float* src = (const float*)d_in[0];
    const float* tgt = (const float*)d_in[1];
    float* out = (float*)d_out;

    // ws: [0,16) acc[4]; [16,32) cnt[4]; [32,36) ticket; [256, ...) partials
    float* acc = (float*)d_ws;
    float* cnt = acc + 4;
    unsigned* ticket = (unsigned*)((char*)d_ws + 32);
    float* part = (float*)((char*)d_ws + 256);  // 16*3*32768*4 B = 6.29 MB

    hipMemsetAsync(d_ws, 0, 256, stream);

    dim3 g1(SRC_CHUNKS, TSPLIT, BATCH);  // 8 x 16 x 4 = 512 blocks
    knn_partial<<<g1, 256, 0, stream>>>(src, tgt, part);

    knn_merge<<<dim3(NSRC_TOT / 256), 256, 0, stream>>>(src, part, acc, cnt, ticket, out);
}

// Round 3
// 117.347 us; speedup vs baseline: 1.3450x; 1.0522x over previous
//
#include <hip/hip_runtime.h>
#include <math.h>

// knnLoss: B=4, N=8192, k=3. Brute-force 3-NN, LDS tiles, forced-packed fp32.
#define BATCH 4
#define NPTS 8192
#define TILE 512            // targets per block tile
#define TSPLIT 16           // NPTS / TILE
#define SRC_PER_BLOCK 512   // 256 threads x 2 sources
#define SRC_CHUNKS 16       // NPTS / SRC_PER_BLOCK
#define NSRC_TOT (BATCH * NPTS)  // 32768

typedef __attribute__((ext_vector_type(2))) float f2;

// Branchless insert into sorted ascending triple; 4 ops via med3.
__device__ __forceinline__ void insert3(float d, float& a0, float& a1, float& a2) {
    float h = fmaxf(a1, d);
    float m = __builtin_amdgcn_fmed3f(a0, a1, d);
    a2 = fminf(a2, h);
    a1 = m;
    a0 = fminf(a0, d);
}

// Merge two sorted-ascending triples -> the sorted 3 smallest of the union. 6 ops.
__device__ __forceinline__ void merge33(float a0, float a1, float a2,
                                        float& b0, float& b1, float& b2) {
    float s0 = fminf(a0, b0);
    float h  = fmaxf(a0, b0);
    float m  = fminf(a1, b1);
    float mm = fminf(a2, b2);
    b1 = fminf(h, m);
    b2 = __builtin_amdgcn_fmed3f(h, m, mm);
    b0 = s0;
}

__global__ __launch_bounds__(256) void knn_partial(const float* __restrict__ src,
                                                   const float* __restrict__ tgt,
                                                   float* __restrict__ part,
                                                   float* __restrict__ hdr) {
    // Entry e (targets 2e,2e+1): ts[2e]={x0,x1,y0,y1}, ts[2e+1]={z0,z1,w0,w1}
    __shared__ float4 ts[TILE / 2 * 2];
    const int tid = threadIdx.x;
    const int sc = blockIdx.x, tc = blockIdx.y, b = blockIdx.z;

    // Zero the reduction header once (merge runs strictly after this kernel).
    if (sc == 0 && tc == 0 && b == 0 && tid < 16) hdr[tid] = 0.0f;

    {
        const float* tb = tgt + ((size_t)b * NPTS + (size_t)tc * TILE + 2 * tid) * 3;
        float x0 = tb[0], y0 = tb[1], z0 = tb[2];
        float x1 = tb[3], y1 = tb[4], z1 = tb[5];
        float w0 = x0 * x0 + y0 * y0 + z0 * z0;
        float w1 = x1 * x1 + y1 * y1 + z1 * z1;
        if (!(x0 != 0.f || y0 != 0.f || z0 != 0.f)) w0 = 3.0e38f;
        if (!(x1 != 0.f || y1 != 0.f || z1 != 0.f)) w1 = 3.0e38f;
        ts[2 * tid + 0] = make_float4(x0, x1, y0, y1);
        ts[2 * tid + 1] = make_float4(z0, z1, w0, w1);
    }
    __syncthreads();

    // 2 sources per thread, packed precomputes in both halves.
    f2 nx[2], ny[2], nz[2], s2[2];
    #pragma unroll
    for (int s = 0; s < 2; ++s) {
        int i = sc * SRC_PER_BLOCK + tid + 256 * s;
        const float* sp = src + ((size_t)b * NPTS + i) * 3;
        float ax = sp[0], ay = sp[1], az = sp[2];
        float q = ax * ax + ay * ay + az * az;
        nx[s] = (f2){-2.f * ax, -2.f * ax};
        ny[s] = (f2){-2.f * ay, -2.f * ay};
        nz[s] = (f2){-2.f * az, -2.f * az};
        s2[s] = (f2){q, q};
    }

    // 4 independent chains: [source][even/odd target]
    float c0[2][2], c1[2][2], c2[2][2];
    #pragma unroll
    for (int s = 0; s < 2; ++s)
        for (int h = 0; h < 2; ++h) { c0[s][h] = c1[s][h] = c2[s][h] = 3e38f; }

    #pragma unroll 4
    for (int e = 0; e < TILE / 2; ++e) {
        float4 p = ts[2 * e + 0];   // ds_read_b128 (broadcast)
        float4 q = ts[2 * e + 1];
        f2 xs = (f2){p.x, p.y};
        f2 ys = (f2){p.z, p.w};
        f2 zs = (f2){q.x, q.y};
        f2 ws = (f2){q.z, q.w};
        #pragma unroll
        for (int s = 0; s < 2; ++s) {
            f2 acc = ws + s2[s];                                // v_pk_add_f32
            acc = __builtin_elementwise_fma(zs, nz[s], acc);    // v_pk_fma_f32
            acc = __builtin_elementwise_fma(ys, ny[s], acc);
            acc = __builtin_elementwise_fma(xs, nx[s], acc);
            insert3(acc.x, c0[s][0], c1[s][0], c2[s][0]);
            insert3(acc.y, c0[s][1], c1[s][1], c2[s][1]);
        }
    }

    // Merge odd chain into even, write sorted triple (coalesced).
    #pragma unroll
    for (int s = 0; s < 2; ++s) {
        merge33(c0[s][1], c1[s][1], c2[s][1], c0[s][0], c1[s][0], c2[s][0]);
        size_t flat = (size_t)b * NPTS + sc * SRC_PER_BLOCK + tid + 256 * s;
        part[((size_t)tc * 3 + 0) * NSRC_TOT + flat] = c0[s][0];
        part[((size_t)tc * 3 + 1) * NSRC_TOT + flat] = c1[s][0];
        part[((size_t)tc * 3 + 2) * NSRC_TOT + flat] = c2[s][0];
    }
}

__global__ __launch_bounds__(256) void knn_merge(const float* __restrict__ src,
                                                 const float* __restrict__ part,
                                                 float* __restrict__ acc,
                                                 float* __restrict__ cnt,
                                                 unsigned* __restrict__ ticket,
                                                 float* __restrict__ out) {
    const int gid = blockIdx.x * 256 + threadIdx.x;  // 0 .. NSRC_TOT-1
    const int b = gid >> 13;                         // uniform per block

    // 48 partial values -> 4 independent sub-triples (ILP), then merge tree.
    float t0[4], t1[4], t2[4];
    #pragma unroll
    for (int c = 0; c < 4; ++c) { t0[c] = t1[c] = t2[c] = 3e38f; }
    #pragma unroll
    for (int q = 0; q < TSPLIT * 3; ++q)
        insert3(part[(size_t)q * NSRC_TOT + gid], t0[q & 3], t1[q & 3], t2[q & 3]);
    merge33(t0[1], t1[1], t2[1], t0[0], t1[0], t2[0]);
    merge33(t0[3], t1[3], t2[3], t0[2], t1[2], t2[2]);
    merge33(t0[2], t1[2], t2[2], t0[0], t1[0], t2[0]);

    float sx = src[(size_t)gid * 3 + 0];
    float sy = src[(size_t)gid * 3 + 1];
    float sz = src[(size_t)gid * 3 + 2];
    bool valid = (sx != 0.f) || (sy != 0.f) || (sz != 0.f);
    float s = valid ? (sqrtf(fmaxf(t0[0], 0.f)) + sqrtf(fmaxf(t1[0], 0.f)) +
                       sqrtf(fmaxf(t2[0], 0.f)))
                    : 0.f;
    float c = valid ? 1.f : 0.f;

    for (int off = 32; off >= 1; off >>= 1) {
        s += __shfl_down(s, off);
        c += __shfl_down(c, off);
    }
    __shared__ float red_s[4], red_c[4];
    int wave = threadIdx.x >> 6, lane = threadIdx.x & 63;
    if (lane == 0) { red_s[wave] = s; red_c[wave] = c; }
    __syncthreads();
    if (threadIdx.x == 0) {
        atomicAdd(&acc[b], red_s[0] + red_s[1] + red_s[2] + red_s[3]);
        atomicAdd(&cnt[b], red_c[0] + red_c[1] + red_c[2] + red_c[3]);
        __threadfence();
        unsigned t = atomicAdd(ticket, 1u);
        if (t == (unsigned)(gridDim.x - 1)) {
            float loss = 0.f;
            #pragma unroll
            for (int bb = 0; bb < BATCH; ++bb) {
                float as = atomicAdd(&acc[bb], 0.f);
                float ac = atomicAdd(&cnt[bb], 0.f);
                loss += as / (ac * 3.0f);
            }
            out[0] = loss * (1.0f / BATCH);
        }
    }
}

extern "C" void kernel_launch(void* const* d_in, const int* in_sizes, int n_in,
                              void* d_out, int out_size, void* d_ws, size_t ws_size,
                              hipStream_t stream) {
    const float* src = (const float*)d_in[0];
    const float* tgt = (const float*)d_in[1];
    float* out = (float*)d_out;

    // ws: [0,16) acc[4]; [16,32) cnt[4]; [32,36) ticket; [64) pad; [256,...) partials
    float* hdr = (float*)d_ws;
    float* acc = hdr;
    float* cnt = hdr + 4;
    unsigned* ticket = (unsigned*)((char*)d_ws + 32);
    float* part = (float*)((char*)d_ws + 256);  // 16*3*32768*4 B = 6.29 MB

    dim3 g1(SRC_CHUNKS, TSPLIT, BATCH);  // 16 x 16 x 4 = 1024 blocks
    knn_partial<<<g1, 256, 0, stream>>>(src, tgt, part, hdr);

    knn_merge<<<dim3(NSRC_TOT / 256), 256, 0, stream>>>(src, part, acc, cnt, ticket, out);
}